// Round 2
// baseline (979.082 us; speedup 1.0000x reference)
//
#include <hip/hip_runtime.h>
#include <hip/hip_bf16.h>
#include <stdint.h>

// ---------------------------------------------------------------------------
// Fused causal attention, N=8192, D=512, fp32 in/out, bf16 MFMA compute.
// Pipeline: cvt(x,W) -> QKV GEMM (V transposed) -> split-KV flash partials
//           -> combine.
// ---------------------------------------------------------------------------

#define N_TOK 8192
#define DIM   512
#define NQB   128          // N / 64 query blocks
#define CCH   12           // KV blocks (of 64) per split-KV chunk
#define MAXCH 11           // ceil(128/12)
#define NCHTOT 748         // sum_{n=1..128} ceil(n/12)

typedef __attribute__((ext_vector_type(8))) short bfrag;     // 8 bf16 (4 VGPR)
typedef __attribute__((ext_vector_type(4))) float facc;      // 4 f32 acc
typedef __attribute__((ext_vector_type(4))) unsigned short us4v;
typedef __attribute__((ext_vector_type(2))) float f32x2v;

#define MFMA16(a, b, c) __builtin_amdgcn_mfma_f32_16x16x32_bf16((a), (b), (c), 0, 0, 0)

__device__ __forceinline__ unsigned short f2bf(float f) {
    union { float f; unsigned int u; } v; v.f = f;
    unsigned int r = v.u + 0x7fffu + ((v.u >> 16) & 1u);   // RNE
    return (unsigned short)(r >> 16);
}
__device__ __forceinline__ float bf2f(unsigned int bits16) {
    union { unsigned int u; float f; } v; v.u = bits16 << 16;
    return v.f;
}

// ------------------------------ fp32 -> bf16 converts ----------------------
__global__ void cvt_x_kernel(const float* __restrict__ src,
                             unsigned short* __restrict__ dst, int n4) {
    int i = blockIdx.x * blockDim.x + threadIdx.x;
    if (i >= n4) return;
    float4 v = ((const float4*)src)[i];
    us4v o; o[0] = f2bf(v.x); o[1] = f2bf(v.y); o[2] = f2bf(v.z); o[3] = f2bf(v.w);
    ((us4v*)dst)[i] = o;
}

__global__ void cvt_w_kernel(const float* __restrict__ wq,
                             const float* __restrict__ wk,
                             const float* __restrict__ wv,
                             unsigned short* __restrict__ dst) {
    int i = blockIdx.x * blockDim.x + threadIdx.x;      // 0..196607
    int g = i >> 16;
    int o = i & 65535;
    const float* s = (g == 0) ? wq : (g == 1) ? wk : wv;
    float4 v = ((const float4*)s)[o];
    us4v p; p[0] = f2bf(v.x); p[1] = f2bf(v.y); p[2] = f2bf(v.z); p[3] = f2bf(v.w);
    ((us4v*)dst)[i] = p;
}

// ------------------------------ QKV projection GEMM ------------------------
// C[m][n] = sum_k x[m,k] * W[n,k] + b[n]   (torch Linear, B^T-layout GEMM)
// grid (64, 8, 3): 128-row x 64-col tiles; z selects Wq/Wk/Wv.
// z<2 -> row-major bf16 out; z==2 -> transposed out VT[512][8192].
__global__ __launch_bounds__(256) void qkv_gemm(
    const unsigned short* __restrict__ xb,   // [8192][512] bf16
    const unsigned short* __restrict__ wb,   // [3][512][512] bf16
    const float* __restrict__ biasq, const float* __restrict__ biask,
    const float* __restrict__ biasv,
    unsigned short* __restrict__ Qb, unsigned short* __restrict__ Kb,
    unsigned short* __restrict__ VTb) {
    const int z    = blockIdx.z;
    const int lane = threadIdx.x & 63;
    const int wv   = threadIdx.x >> 6;        // 4 waves: 32-row strips
    const int r0   = blockIdx.x * 128 + wv * 32;
    const int c0   = blockIdx.y * 64;
    const unsigned short* w = wb + z * 262144;
    const float* bias = (z == 0) ? biasq : (z == 1) ? biask : biasv;
    const int lr  = lane & 15;
    const int lkc = lane >> 4;
    const int lk  = lkc * 8;

    facc acc[2][4] = {};
    const unsigned short* ap0 = xb + (size_t)(r0 + lr) * 512 + lk;
    const unsigned short* bp0 = w  + (size_t)(c0 + lr) * 512 + lk;

#pragma unroll
    for (int s = 0; s < 16; ++s) {
        const int kk = s * 32;
        bfrag a0 = *(const bfrag*)(ap0 + kk);
        bfrag a1 = *(const bfrag*)(ap0 + 16 * 512 + kk);
        bfrag b0 = *(const bfrag*)(bp0 + kk);
        bfrag b1 = *(const bfrag*)(bp0 + 16 * 512 + kk);
        bfrag b2 = *(const bfrag*)(bp0 + 32 * 512 + kk);
        bfrag b3 = *(const bfrag*)(bp0 + 48 * 512 + kk);
        acc[0][0] = MFMA16(a0, b0, acc[0][0]);
        acc[0][1] = MFMA16(a0, b1, acc[0][1]);
        acc[0][2] = MFMA16(a0, b2, acc[0][2]);
        acc[0][3] = MFMA16(a0, b3, acc[0][3]);
        acc[1][0] = MFMA16(a1, b0, acc[1][0]);
        acc[1][1] = MFMA16(a1, b1, acc[1][1]);
        acc[1][2] = MFMA16(a1, b2, acc[1][2]);
        acc[1][3] = MFMA16(a1, b3, acc[1][3]);
    }

    const int rbase = lkc * 4;
    if (z < 2) {
        unsigned short* out = (z == 0) ? Qb : Kb;
#pragma unroll
        for (int i = 0; i < 2; ++i)
#pragma unroll
            for (int j = 0; j < 4; ++j) {
                const int col = c0 + j * 16 + lr;
                const float bv_ = bias[col];
#pragma unroll
                for (int r = 0; r < 4; ++r) {
                    const int row = r0 + i * 16 + rbase + r;
                    out[(size_t)row * 512 + col] = f2bf(acc[i][j][r] + bv_);
                }
            }
    } else {
#pragma unroll
        for (int i = 0; i < 2; ++i)
#pragma unroll
            for (int j = 0; j < 4; ++j) {
                const int col = c0 + j * 16 + lr;
                const float bv_ = bias[col];
                us4v pk;
#pragma unroll
                for (int r = 0; r < 4; ++r) pk[r] = f2bf(acc[i][j][r] + bv_);
                *(us4v*)(VTb + (size_t)col * 8192 + (r0 + i * 16 + rbase)) = pk;
            }
    }
}

// ------------------------------ flash attention partials -------------------
// grid (128 qb, 11 chunk), 512 threads (8 waves).
// Wave layout QK^T: 4 row-strips(16) x 2 col-halves(32). Q in registers.
// PV: wave w owns O cols [64w, 64w+64). Online softmax in LDS.
__global__ __launch_bounds__(512, 2) void attn_partial(
    const unsigned short* __restrict__ Qb, const unsigned short* __restrict__ Kb,
    const unsigned short* __restrict__ VTb,
    unsigned short* __restrict__ Opart, float* __restrict__ ml) {
    const int qb = blockIdx.x;
    const int c  = blockIdx.y;
    const int nch = (qb + 12) / 12;
    if (c >= nch) return;
    const int kb0 = c * CCH;
    const int kb1 = min(kb0 + CCH, qb + 1);
    const int a_ = qb / 12, b_ = qb % 12;
    const int idx = 6 * a_ * (a_ + 1) + b_ * (a_ + 1) + c;

    const int tid  = threadIdx.x;
    const int lane = tid & 63;
    const int wv   = tid >> 6;
    const int sr   = wv & 3;     // row strip for QK^T
    const int ch   = wv >> 2;    // col half for QK^T
    const int lr   = lane & 15;
    const int lkc  = lane >> 4;
    const int lk   = lkc * 8;
    const int qrow0 = qb * 64;

    // S stride 65: softmax read bank = (row + 8*sub + j) % 32 -> 2-way (free).
    // (stride 72 gave 16-way: 8*row+8*sub all = 0 mod 8 -> 4 banks)
    __shared__ float          S_lds[64][65];
    __shared__ unsigned short P_lds[64][72];
    __shared__ float m_lds[64], l_lds[64], sc_lds[64];

    if (tid < 64) { m_lds[tid] = -1e30f; l_lds[tid] = 0.f; }

    // Q fragments for this wave's 16-row strip: full K=512
    bfrag q[16];
    {
        const unsigned short* qp = Qb + (size_t)(qrow0 + sr * 16 + lr) * 512 + lk;
#pragma unroll
        for (int s = 0; s < 16; ++s) q[s] = *(const bfrag*)(qp + s * 32);
    }
    facc o[4][4] = {};
    __syncthreads();

    const int row = tid >> 3;     // softmax: 8 threads per row
    const int sub = tid & 7;
    const float sm_scale = 0.044194173824159216f;   // 1/sqrt(512)

    for (int kb = kb0; kb < kb1; ++kb) {
        const int cb = kb * 64;
        // ---- QK^T ----
#pragma unroll
        for (int tc = 0; tc < 2; ++tc) {
            facc sacc = {};
            const unsigned short* kp =
                Kb + (size_t)(cb + ch * 32 + tc * 16 + lr) * 512 + lk;
#pragma unroll
            for (int s = 0; s < 16; ++s) {
                bfrag bf = *(const bfrag*)(kp + s * 32);
                sacc = MFMA16(q[s], bf, sacc);
            }
#pragma unroll
            for (int r = 0; r < 4; ++r)
                S_lds[sr * 16 + lkc * 4 + r][ch * 32 + tc * 16 + lr] = sacc[r];
        }
        __syncthreads();

        // ---- online softmax (rows of 64 cols; 8 threads/row) ----
        {
            const int grow  = qrow0 + row;
            const bool diag = (kb == qb);
            float sv[8];
#pragma unroll
            for (int j = 0; j < 8; ++j) {
                float v = S_lds[row][sub * 8 + j] * sm_scale;
                if (diag && (cb + sub * 8 + j > grow)) v = -1e30f;
                sv[j] = v;
            }
            float mx = sv[0];
#pragma unroll
            for (int j = 1; j < 8; ++j) mx = fmaxf(mx, sv[j]);
            mx = fmaxf(mx, __shfl_xor(mx, 1));
            mx = fmaxf(mx, __shfl_xor(mx, 2));
            mx = fmaxf(mx, __shfl_xor(mx, 4));
            const float m_old = m_lds[row];
            const float m_new = fmaxf(m_old, mx);   // idempotent across the 8 threads
            float sum = 0.f;
            bfrag pv_;
#pragma unroll
            for (int j = 0; j < 8; ++j) {
                float p = __expf(sv[j] - m_new);
                sum += p;
                pv_[j] = (short)f2bf(p);
            }
            sum += __shfl_xor(sum, 1);
            sum += __shfl_xor(sum, 2);
            sum += __shfl_xor(sum, 4);
            if (sub == 0) {                          // single writer: no RMW race
                const float scl = __expf(m_old - m_new);
                sc_lds[row] = scl;
                m_lds[row]  = m_new;
                l_lds[row]  = l_lds[row] * scl + sum;
            }
            *(bfrag*)(&P_lds[row][sub * 8]) = pv_;   // 16B aligned (stride 144B)
        }
        __syncthreads();

        // ---- rescale accumulators ----
#pragma unroll
        for (int i = 0; i < 4; ++i) {
            float s0 = sc_lds[i * 16 + lkc * 4 + 0];
            float s1 = sc_lds[i * 16 + lkc * 4 + 1];
            float s2 = sc_lds[i * 16 + lkc * 4 + 2];
            float s3 = sc_lds[i * 16 + lkc * 4 + 3];
#pragma unroll
            for (int j = 0; j < 4; ++j) {
                o[i][j][0] *= s0; o[i][j][1] *= s1;
                o[i][j][2] *= s2; o[i][j][3] *= s3;
            }
        }
        // ---- PV: O[:, 64w..] += P @ V ----
#pragma unroll
        for (int s = 0; s < 2; ++s) {
            bfrag pa[4], vb[4];
#pragma unroll
            for (int i = 0; i < 4; ++i)
                pa[i] = *(const bfrag*)(&P_lds[i * 16 + lr][s * 32 + lk]);
#pragma unroll
            for (int j = 0; j < 4; ++j)
                vb[j] = *(const bfrag*)(VTb + (size_t)(wv * 64 + j * 16 + lr) * 8192
                                        + cb + s * 32 + lk);
#pragma unroll
            for (int i = 0; i < 4; ++i)
#pragma unroll
                for (int j = 0; j < 4; ++j)
                    o[i][j] = MFMA16(pa[i], vb[j], o[i][j]);
        }
        // no barrier needed here: next QK^T writes S (not P/scale), and the next
        // softmax's P/m/l writes are fenced by the next iteration's first barrier
    }

    // ---- epilogue: unnormalized partial O (bf16) + m/l stats ----
    {
        const size_t obase = (size_t)idx * (64 * 512);
#pragma unroll
        for (int i = 0; i < 4; ++i)
#pragma unroll
            for (int j = 0; j < 4; ++j) {
                const int colb = wv * 64 + j * 16 + lr;
#pragma unroll
                for (int r = 0; r < 4; ++r) {
                    const int rrow = i * 16 + lkc * 4 + r;
                    Opart[obase + (size_t)rrow * 512 + colb] = f2bf(o[i][j][r]);
                }
            }
        if (tid < 64) {
            ml[(size_t)idx * 128 + tid * 2 + 0] = m_lds[tid];
            ml[(size_t)idx * 128 + tid * 2 + 1] = l_lds[tid];
        }
    }
}

// ------------------------------ split-KV combine ---------------------------
__global__ __launch_bounds__(256) void combine_k(
    const unsigned short* __restrict__ Opart, const float* __restrict__ ml,
    float* __restrict__ out) {
    const int qb  = blockIdx.x;
    const int nch = (qb + 12) / 12;
    const int a_ = qb / 12, b_ = qb % 12;
    const int base = 6 * a_ * (a_ + 1) + b_ * (a_ + 1);
    const int tid  = threadIdx.x;
    __shared__ float wts[MAXCH][64];

    if (tid < 64) {
        float M = -1e30f;
        for (int cc = 0; cc < nch; ++cc)
            M = fmaxf(M, ml[(size_t)(base + cc) * 128 + tid * 2]);
        float den = 0.f;
        for (int cc = 0; cc < nch; ++cc) {
            float mc = ml[(size_t)(base + cc) * 128 + tid * 2];
            float lc = ml[(size_t)(base + cc) * 128 + tid * 2 + 1];
            den += lc * __expf(mc - M);
        }
        const float inv = 1.f / den;
        for (int cc = 0; cc < nch; ++cc) {
            float mc = ml[(size_t)(base + cc) * 128 + tid * 2];
            wts[cc][tid] = __expf(mc - M) * inv;
        }
    }
    __syncthreads();

    for (int r = 0; r < 64; ++r) {
        float a0 = 0.f, a1 = 0.f;
        for (int cc = 0; cc < nch; ++cc) {
            const float w = wts[cc][r];
            const unsigned int pk = *(const unsigned int*)(
                Opart + (size_t)(base + cc) * (64 * 512) + r * 512 + tid * 2);
            a0 += w * bf2f(pk & 0xffffu);
            a1 += w * bf2f(pk >> 16);
        }
        f32x2v res; res[0] = a0; res[1] = a1;
        *(f32x2v*)(out + (size_t)(qb * 64 + r) * 512 + tid * 2) = res;
    }
}

// ------------------------------ launcher -----------------------------------
extern "C" void kernel_launch(void* const* d_in, const int* in_sizes, int n_in,
                              void* d_out, int out_size, void* d_ws, size_t ws_size,
                              hipStream_t stream) {
    const float* x  = (const float*)d_in[0];
    // d_in[1] = mask: deliberately unread (causal mask computed implicitly)
    const float* Wq = (const float*)d_in[2];
    const float* bq = (const float*)d_in[3];
    const float* Wk = (const float*)d_in[4];
    const float* bk = (const float*)d_in[5];
    const float* Wv = (const float*)d_in[6];
    const float* bv = (const float*)d_in[7];
    float* out = (float*)d_out;

    char* ws = (char*)d_ws;
    unsigned short* xb  = (unsigned short*)(ws);                 //  8 MB
    unsigned short* Wb  = (unsigned short*)(ws + 8388608);       //  1.5 MB
    unsigned short* Qb  = (unsigned short*)(ws + 9961472);       //  8 MB
    unsigned short* Kb  = (unsigned short*)(ws + 18350080);      //  8 MB
    unsigned short* VTb = (unsigned short*)(ws + 26738688);      //  8 MB
    unsigned short* Op  = (unsigned short*)(ws + 35127296);      // 46.7 MB
    float*          mlp = (float*)(ws + 84148224);               //  0.37 MB

    hipLaunchKernelGGL(cvt_x_kernel, dim3(4096), dim3(256), 0, stream, x, xb, 1048576);
    hipLaunchKernelGGL(cvt_w_kernel, dim3(768), dim3(256), 0, stream, Wq, Wk, Wv, Wb);
    hipLaunchKernelGGL(qkv_gemm, dim3(64, 8, 3), dim3(256), 0, stream,
                       xb, Wb, bq, bk, bv, Qb, Kb, VTb);
    hipLaunchKernelGGL(attn_partial, dim3(NQB, MAXCH), dim3(512), 0, stream,
                       Qb, Kb, VTb, Op, mlp);
    hipLaunchKernelGGL(combine_k, dim3(NQB), dim3(256), 0, stream, Op, mlp, out);
}

// Round 4
// 537.765 us; speedup vs baseline: 1.8207x; 1.8207x over previous
//
#include <hip/hip_runtime.h>
#include <hip/hip_bf16.h>
#include <stdint.h>

// ---------------------------------------------------------------------------
// Fused causal attention, N=8192, D=512, fp32 in/out, bf16 MFMA compute.
// Pipeline: cvt(x,W) -> QKV GEMM (V transposed) -> split-KV flash partials
//           (K staged in LDS via async DMA, double-buffered) -> combine.
// ---------------------------------------------------------------------------

#define N_TOK 8192
#define DIM   512
#define NQB   128          // N / 64 query blocks
#define CCH   12           // KV blocks (of 64) per split-KV chunk
#define MAXCH 11           // ceil(128/12)
#define NCHTOT 748         // number of live (qb, c) blocks

typedef __attribute__((ext_vector_type(8))) short bfrag;     // 8 bf16 (4 VGPR)
typedef __attribute__((ext_vector_type(4))) float facc;      // 4 f32 acc
typedef __attribute__((ext_vector_type(4))) unsigned short us4v;
typedef __attribute__((ext_vector_type(2))) float f32x2v;

#define MFMA16(a, b, c) __builtin_amdgcn_mfma_f32_16x16x32_bf16((a), (b), (c), 0, 0, 0)

__device__ __forceinline__ unsigned short f2bf(float f) {
    union { float f; unsigned int u; } v; v.f = f;
    unsigned int r = v.u + 0x7fffu + ((v.u >> 16) & 1u);   // RNE
    return (unsigned short)(r >> 16);
}
__device__ __forceinline__ float bf2f(unsigned int bits16) {
    union { unsigned int u; float f; } v; v.u = bits16 << 16;
    return v.f;
}
// async 16B global->LDS DMA (lane l writes lds + l*16; global src is per-lane)
__device__ __forceinline__ void cp16(const unsigned short* g, unsigned short* l) {
    __builtin_amdgcn_global_load_lds(
        (const __attribute__((address_space(1))) void*)g,
        (__attribute__((address_space(3))) void*)l, 16, 0, 0);
}

// idx of (qb, c) in the c-major flat block order:
// for c in 0..10: for qb in 12c..127  -> idx = qb + 122c - 6c^2
__device__ __forceinline__ int part_idx(int qb, int c) {
    return qb + 122 * c - 6 * c * c;
}

// ------------------------------ fp32 -> bf16 converts ----------------------
__global__ void cvt_x_kernel(const float* __restrict__ src,
                             unsigned short* __restrict__ dst, int n4) {
    int i = blockIdx.x * blockDim.x + threadIdx.x;
    if (i >= n4) return;
    float4 v = ((const float4*)src)[i];
    us4v o; o[0] = f2bf(v.x); o[1] = f2bf(v.y); o[2] = f2bf(v.z); o[3] = f2bf(v.w);
    ((us4v*)dst)[i] = o;
}

__global__ void cvt_w_kernel(const float* __restrict__ wq,
                             const float* __restrict__ wk,
                             const float* __restrict__ wv,
                             unsigned short* __restrict__ dst) {
    int i = blockIdx.x * blockDim.x + threadIdx.x;      // 0..196607
    int g = i >> 16;
    int o = i & 65535;
    const float* s = (g == 0) ? wq : (g == 1) ? wk : wv;
    float4 v = ((const float4*)s)[o];
    us4v p; p[0] = f2bf(v.x); p[1] = f2bf(v.y); p[2] = f2bf(v.z); p[3] = f2bf(v.w);
    ((us4v*)dst)[i] = p;
}

// ------------------------------ QKV projection GEMM ------------------------
__global__ __launch_bounds__(256) void qkv_gemm(
    const unsigned short* __restrict__ xb,   // [8192][512] bf16
    const unsigned short* __restrict__ wb,   // [3][512][512] bf16
    const float* __restrict__ biasq, const float* __restrict__ biask,
    const float* __restrict__ biasv,
    unsigned short* __restrict__ Qb, unsigned short* __restrict__ Kb,
    unsigned short* __restrict__ VTb) {
    const int z    = blockIdx.z;
    const int lane = threadIdx.x & 63;
    const int wv   = threadIdx.x >> 6;        // 4 waves: 32-row strips
    const int r0   = blockIdx.x * 128 + wv * 32;
    const int c0   = blockIdx.y * 64;
    const unsigned short* w = wb + z * 262144;
    const float* bias = (z == 0) ? biasq : (z == 1) ? biask : biasv;
    const int lr  = lane & 15;
    const int lkc = lane >> 4;
    const int lk  = lkc * 8;

    facc acc[2][4] = {};
    const unsigned short* ap0 = xb + (size_t)(r0 + lr) * 512 + lk;
    const unsigned short* bp0 = w  + (size_t)(c0 + lr) * 512 + lk;

#pragma unroll
    for (int s = 0; s < 16; ++s) {
        const int kk = s * 32;
        bfrag a0 = *(const bfrag*)(ap0 + kk);
        bfrag a1 = *(const bfrag*)(ap0 + 16 * 512 + kk);
        bfrag b0 = *(const bfrag*)(bp0 + kk);
        bfrag b1 = *(const bfrag*)(bp0 + 16 * 512 + kk);
        bfrag b2 = *(const bfrag*)(bp0 + 32 * 512 + kk);
        bfrag b3 = *(const bfrag*)(bp0 + 48 * 512 + kk);
        acc[0][0] = MFMA16(a0, b0, acc[0][0]);
        acc[0][1] = MFMA16(a0, b1, acc[0][1]);
        acc[0][2] = MFMA16(a0, b2, acc[0][2]);
        acc[0][3] = MFMA16(a0, b3, acc[0][3]);
        acc[1][0] = MFMA16(a1, b0, acc[1][0]);
        acc[1][1] = MFMA16(a1, b1, acc[1][1]);
        acc[1][2] = MFMA16(a1, b2, acc[1][2]);
        acc[1][3] = MFMA16(a1, b3, acc[1][3]);
    }

    const int rbase = lkc * 4;
    if (z < 2) {
        unsigned short* out = (z == 0) ? Qb : Kb;
#pragma unroll
        for (int i = 0; i < 2; ++i)
#pragma unroll
            for (int j = 0; j < 4; ++j) {
                const int col = c0 + j * 16 + lr;
                const float bv_ = bias[col];
#pragma unroll
                for (int r = 0; r < 4; ++r) {
                    const int row = r0 + i * 16 + rbase + r;
                    out[(size_t)row * 512 + col] = f2bf(acc[i][j][r] + bv_);
                }
            }
    } else {
#pragma unroll
        for (int i = 0; i < 2; ++i)
#pragma unroll
            for (int j = 0; j < 4; ++j) {
                const int col = c0 + j * 16 + lr;
                const float bv_ = bias[col];
                us4v pk;
#pragma unroll
                for (int r = 0; r < 4; ++r) pk[r] = f2bf(acc[i][j][r] + bv_);
                *(us4v*)(VTb + (size_t)col * 8192 + (r0 + i * 16 + rbase)) = pk;
            }
    }
}

// ------------------------------ flash attention partials -------------------
// 748 blocks (c-major, XCD-chunked), 512 threads (8 waves).
// K tiles staged in LDS by async DMA, double-buffered, XOR-swizzled.
__global__ __launch_bounds__(512, 2) void attn_partial(
    const unsigned short* __restrict__ Qb, const unsigned short* __restrict__ Kb,
    const unsigned short* __restrict__ VTb,
    unsigned short* __restrict__ Opart, float* __restrict__ ml) {
    // ---- bijective chunked XCD swizzle (m204): consecutive idx -> same XCD
    const int hb   = blockIdx.x;                    // [0,748)
    const int xcd  = hb & 7, pos = hb >> 3;         // q=93, r=4
    const int idx  = (xcd < 4 ? xcd * 94 : 376 + (xcd - 4) * 93) + pos;
    // ---- invert c-major flat order: cum(c) = 134c - 6c^2
    int c = 0;
#pragma unroll
    for (int cc = 1; cc < MAXCH; ++cc)
        if (idx >= 134 * cc - 6 * cc * cc) c = cc;
    const int qb  = 12 * c + (idx - (134 * c - 6 * c * c));
    const int kb0 = c * CCH;
    const int kb1 = min(kb0 + CCH, qb + 1);

    const int tid  = threadIdx.x;
    const int lane = tid & 63;
    const int wv   = tid >> 6;
    const int sr   = wv & 3;     // row strip for QK^T
    const int ch   = wv >> 2;    // col half for QK^T
    const int lr   = lane & 15;
    const int lkc  = lane >> 4;
    const int lk   = lkc * 8;
    const int qrow0 = qb * 64;

    __shared__ unsigned short Klds[2][64 * 512];   // 2 x 64KB, XOR-swizzled rows
    __shared__ float          S_lds[64][65];
    __shared__ unsigned short P_lds[64][72];
    __shared__ float m_lds[64], l_lds[64], sc_lds[64];

    if (tid < 64) { m_lds[tid] = -1e30f; l_lds[tid] = 0.f; }

    // K DMA: wave wv stages rows {wv, wv+8, ..., wv+56}. Within a row the 16B
    // slot s holds global 16B-block (s ^ (row&7)) -> ds_read applies same XOR.
    auto stage_k = [&](int kb, int buf) {
        const unsigned short* src = Kb + (size_t)kb * (64 * 512) + (lane ^ wv) * 8;
#pragma unroll
        for (int i = 0; i < 8; ++i) {
            const int rl = wv + 8 * i;
            cp16(src + (size_t)rl * 512, &Klds[buf][rl * 512]);
        }
    };

    // Q fragments for this wave's 16-row strip: full K=512
    bfrag q[16];
    {
        const unsigned short* qp = Qb + (size_t)(qrow0 + sr * 16 + lr) * 512 + lk;
#pragma unroll
        for (int s = 0; s < 16; ++s) q[s] = *(const bfrag*)(qp + s * 32);
    }
    facc o[4][4] = {};
    stage_k(kb0, 0);
    __syncthreads();

    const int row = tid >> 3;     // softmax: 8 threads per row
    const int sub = tid & 7;
    const float sm_scale = 0.044194173824159216f;   // 1/sqrt(512)
    int cur = 0;

    for (int kb = kb0; kb < kb1; ++kb) {
        const int cb = kb * 64;
        // ---- prefetch next K tile (async, lands behind this tile's barrier)
        if (kb + 1 < kb1) stage_k(kb + 1, cur ^ 1);
        // ---- hoist V loads for this tile (consumed at PV)
        bfrag vbf[2][4];
#pragma unroll
        for (int s = 0; s < 2; ++s)
#pragma unroll
            for (int j = 0; j < 4; ++j)
                vbf[s][j] = *(const bfrag*)(VTb + (size_t)(wv * 64 + j * 16 + lr) * 8192
                                            + cb + s * 32 + lk);
        // ---- QK^T from LDS ----
#pragma unroll
        for (int tc = 0; tc < 2; ++tc) {
            facc sacc = {};
            const int rl = ch * 32 + tc * 16 + lr;
            const unsigned short* kbase = &Klds[cur][rl * 512];
            const int rx = rl & 7;
#pragma unroll
            for (int s = 0; s < 16; ++s) {
                const int slot = (s * 4 + lkc) ^ rx;
                bfrag bf = *(const bfrag*)(kbase + slot * 8);
                sacc = MFMA16(q[s], bf, sacc);
            }
#pragma unroll
            for (int r = 0; r < 4; ++r)
                S_lds[sr * 16 + lkc * 4 + r][ch * 32 + tc * 16 + lr] = sacc[r];
        }
        __syncthreads();   // A: S complete

        // ---- online softmax (rows of 64 cols; 8 threads/row) ----
        {
            const int grow  = qrow0 + row;
            const bool diag = (kb == qb);
            float sv[8];
#pragma unroll
            for (int j = 0; j < 8; ++j) {
                float v = S_lds[row][sub * 8 + j] * sm_scale;
                if (diag && (cb + sub * 8 + j > grow)) v = -1e30f;
                sv[j] = v;
            }
            float mx = sv[0];
#pragma unroll
            for (int j = 1; j < 8; ++j) mx = fmaxf(mx, sv[j]);
            mx = fmaxf(mx, __shfl_xor(mx, 1));
            mx = fmaxf(mx, __shfl_xor(mx, 2));
            mx = fmaxf(mx, __shfl_xor(mx, 4));
            const float m_old = m_lds[row];
            const float m_new = fmaxf(m_old, mx);
            float sum = 0.f;
            bfrag pv_;
#pragma unroll
            for (int j = 0; j < 8; ++j) {
                float p = __expf(sv[j] - m_new);
                sum += p;
                pv_[j] = (short)f2bf(p);
            }
            sum += __shfl_xor(sum, 1);
            sum += __shfl_xor(sum, 2);
            sum += __shfl_xor(sum, 4);
            if (sub == 0) {                          // single writer
                const float scl = __expf(m_old - m_new);
                sc_lds[row] = scl;
                m_lds[row]  = m_new;
                l_lds[row]  = l_lds[row] * scl + sum;
            }
            *(bfrag*)(&P_lds[row][sub * 8]) = pv_;   // 16B aligned (144B stride)
        }
        __syncthreads();   // B: P, m/l/sc complete

        // ---- rescale accumulators ----
#pragma unroll
        for (int i = 0; i < 4; ++i) {
            float s0 = sc_lds[i * 16 + lkc * 4 + 0];
            float s1 = sc_lds[i * 16 + lkc * 4 + 1];
            float s2 = sc_lds[i * 16 + lkc * 4 + 2];
            float s3 = sc_lds[i * 16 + lkc * 4 + 3];
#pragma unroll
            for (int j = 0; j < 4; ++j) {
                o[i][j][0] *= s0; o[i][j][1] *= s1;
                o[i][j][2] *= s2; o[i][j][3] *= s3;
            }
        }
        // ---- PV: O[:, 64w..] += P @ V (V frags already in regs) ----
#pragma unroll
        for (int s = 0; s < 2; ++s) {
            bfrag pa[4];
#pragma unroll
            for (int i = 0; i < 4; ++i)
                pa[i] = *(const bfrag*)(&P_lds[i * 16 + lr][s * 32 + lk]);
#pragma unroll
            for (int i = 0; i < 4; ++i)
#pragma unroll
                for (int j = 0; j < 4; ++j)
                    o[i][j] = MFMA16(pa[i], vbf[s][j], o[i][j]);
        }
        __syncthreads();   // C: P reads done; next K DMA (own waves) drained
        cur ^= 1;
    }

    // ---- epilogue: unnormalized partial O (bf16) + m/l stats ----
    {
        const size_t obase = (size_t)idx * (64 * 512);
#pragma unroll
        for (int i = 0; i < 4; ++i)
#pragma unroll
            for (int j = 0; j < 4; ++j) {
                const int colb = wv * 64 + j * 16 + lr;
#pragma unroll
                for (int r = 0; r < 4; ++r) {
                    const int rrow = i * 16 + lkc * 4 + r;
                    Opart[obase + (size_t)rrow * 512 + colb] = f2bf(o[i][j][r]);
                }
            }
        if (tid < 64) {
            ml[(size_t)idx * 128 + tid * 2 + 0] = m_lds[tid];
            ml[(size_t)idx * 128 + tid * 2 + 1] = l_lds[tid];
        }
    }
}

// ------------------------------ split-KV combine ---------------------------
// grid (128, 8): block = (qb, 8-row group). Inner chunk loop is compile-time
// (11 iters, zero-weighted beyond nch) -> 88 independent loads per thread.
__global__ __launch_bounds__(256) void combine_k(
    const unsigned short* __restrict__ Opart, const float* __restrict__ ml,
    float* __restrict__ out) {
    const int qb  = blockIdx.x;
    const int rg  = blockIdx.y;            // 8-row group within the 64-row qb
    const int nch = qb / 12 + 1;
    const int tid = threadIdx.x;
    __shared__ float wts[MAXCH][8];

    if (tid < 8) {
        const int lrow = rg * 8 + tid;     // local row in [0,64)
        float M = -1e30f;
        for (int cc = 0; cc < nch; ++cc)
            M = fmaxf(M, ml[(size_t)part_idx(qb, cc) * 128 + lrow * 2]);
        float den = 0.f;
        for (int cc = 0; cc < nch; ++cc) {
            float mc = ml[(size_t)part_idx(qb, cc) * 128 + lrow * 2];
            float lc = ml[(size_t)part_idx(qb, cc) * 128 + lrow * 2 + 1];
            den += lc * __expf(mc - M);
        }
        const float inv = 1.f / den;
#pragma unroll
        for (int cc = 0; cc < MAXCH; ++cc)
            wts[cc][tid] = (cc < nch)
                ? __expf(ml[(size_t)part_idx(qb, cc) * 128 + lrow * 2] - M) * inv
                : 0.f;
    }
    __syncthreads();

    float a0[8] = {}, a1[8] = {};
#pragma unroll
    for (int cc = 0; cc < MAXCH; ++cc) {
        // part_idx is always in [0,748) even for cc>=nch (weight 0, data finite)
        const size_t base = (size_t)part_idx(qb, cc) * (64 * 512);
#pragma unroll
        for (int r = 0; r < 8; ++r) {
            const unsigned int pk = *(const unsigned int*)(
                Opart + base + (size_t)(rg * 8 + r) * 512 + tid * 2);
            const float w = wts[cc][r];
            a0[r] += w * bf2f(pk & 0xffffu);
            a1[r] += w * bf2f(pk >> 16);
        }
    }
#pragma unroll
    for (int r = 0; r < 8; ++r) {
        f32x2v res; res[0] = a0[r]; res[1] = a1[r];
        *(f32x2v*)(out + (size_t)(qb * 64 + rg * 8 + r) * 512 + tid * 2) = res;
    }
}

// ------------------------------ launcher -----------------------------------
extern "C" void kernel_launch(void* const* d_in, const int* in_sizes, int n_in,
                              void* d_out, int out_size, void* d_ws, size_t ws_size,
                              hipStream_t stream) {
    const float* x  = (const float*)d_in[0];
    // d_in[1] = mask: deliberately unread (causal mask computed implicitly)
    const float* Wq = (const float*)d_in[2];
    const float* bq = (const float*)d_in[3];
    const float* Wk = (const float*)d_in[4];
    const float* bk = (const float*)d_in[5];
    const float* Wv = (const float*)d_in[6];
    const float* bv = (const float*)d_in[7];
    float* out = (float*)d_out;

    char* ws = (char*)d_ws;
    unsigned short* xb  = (unsigned short*)(ws);                 //  8 MB
    unsigned short* Wb  = (unsigned short*)(ws + 8388608);       //  1.5 MB
    unsigned short* Qb  = (unsigned short*)(ws + 9961472);       //  8 MB
    unsigned short* Kb  = (unsigned short*)(ws + 18350080);      //  8 MB
    unsigned short* VTb = (unsigned short*)(ws + 26738688);      //  8 MB
    unsigned short* Op  = (unsigned short*)(ws + 35127296);      // 46.7 MB
    float*          mlp = (float*)(ws + 84148224);               //  0.37 MB

    hipLaunchKernelGGL(cvt_x_kernel, dim3(4096), dim3(256), 0, stream, x, xb, 1048576);
    hipLaunchKernelGGL(cvt_w_kernel, dim3(768), dim3(256), 0, stream, Wq, Wk, Wv, Wb);
    hipLaunchKernelGGL(qkv_gemm, dim3(64, 8, 3), dim3(256), 0, stream,
                       xb, Wb, bq, bk, bv, Qb, Kb, VTb);
    hipLaunchKernelGGL(attn_partial, dim3(NCHTOT), dim3(512), 0, stream,
                       Qb, Kb, VTb, Op, mlp);
    hipLaunchKernelGGL(combine_k, dim3(NQB, 8), dim3(256), 0, stream, Op, mlp, out);
}

// Round 6
// 478.513 us; speedup vs baseline: 2.0461x; 1.1238x over previous
//
#include <hip/hip_runtime.h>
#include <hip/hip_bf16.h>
#include <stdint.h>

// ---------------------------------------------------------------------------
// Fused causal attention, N=8192, D=512, fp32 in/out, bf16 MFMA compute.
// Pipeline: cvt(x,W) -> QKV GEMM (LDS-staged, V transposed) ->
//           split-KV flash partials (K in LDS via async DMA) -> combine.
// ---------------------------------------------------------------------------

#define N_TOK 8192
#define DIM   512
#define NQB   128          // N / 64 query blocks
#define CCH   12           // KV blocks (of 64) per split-KV chunk
#define MAXCH 11           // ceil(128/12)
#define NCHTOT 748         // number of live (qb, c) blocks

typedef __attribute__((ext_vector_type(8))) short bfrag;     // 8 bf16 (4 VGPR)
typedef __attribute__((ext_vector_type(4))) float facc;      // 4 f32 acc
typedef __attribute__((ext_vector_type(4))) unsigned short us4v;
typedef __attribute__((ext_vector_type(2))) float f32x2v;

#define MFMA16(a, b, c) __builtin_amdgcn_mfma_f32_16x16x32_bf16((a), (b), (c), 0, 0, 0)

__device__ __forceinline__ unsigned short f2bf(float f) {
    union { float f; unsigned int u; } v; v.f = f;
    unsigned int r = v.u + 0x7fffu + ((v.u >> 16) & 1u);   // RNE
    return (unsigned short)(r >> 16);
}
__device__ __forceinline__ float bf2f(unsigned int bits16) {
    union { unsigned int u; float f; } v; v.u = bits16 << 16;
    return v.f;
}
// async 16B global->LDS DMA. lds base must be wave-uniform; lane l writes
// lds + l*16. global src IS per-lane (pre-swizzle source for swizzled LDS).
__device__ __forceinline__ void cp16(const unsigned short* g, const unsigned short* l) {
    __builtin_amdgcn_global_load_lds(
        (const __attribute__((address_space(1))) void*)g,
        (__attribute__((address_space(3))) void*)l, 16, 0, 0);
}

// idx of (qb, c) in the c-major flat block order:
// for c in 0..10: for qb in 12c..127  -> idx = qb + 122c - 6c^2
__device__ __forceinline__ int part_idx(int qb, int c) {
    return qb + 122 * c - 6 * c * c;
}

// ------------------------------ fp32 -> bf16 converts ----------------------
__global__ void cvt_x_kernel(const float* __restrict__ src,
                             unsigned short* __restrict__ dst, int n4) {
    int i = blockIdx.x * blockDim.x + threadIdx.x;
    if (i >= n4) return;
    float4 v = ((const float4*)src)[i];
    us4v o; o[0] = f2bf(v.x); o[1] = f2bf(v.y); o[2] = f2bf(v.z); o[3] = f2bf(v.w);
    ((us4v*)dst)[i] = o;
}

__global__ void cvt_w_kernel(const float* __restrict__ wq,
                             const float* __restrict__ wk,
                             const float* __restrict__ wv,
                             unsigned short* __restrict__ dst) {
    int i = blockIdx.x * blockDim.x + threadIdx.x;      // 0..196607
    int g = i >> 16;
    int o = i & 65535;
    const float* s = (g == 0) ? wq : (g == 1) ? wk : wv;
    float4 v = ((const float4*)s)[o];
    us4v p; p[0] = f2bf(v.x); p[1] = f2bf(v.y); p[2] = f2bf(v.z); p[3] = f2bf(v.w);
    ((us4v*)dst)[i] = p;
}

// ------------------------------ QKV projection GEMM ------------------------
// C[m][n] = sum_k x[m,k] * W[n,k] + b[n].  Tile 128x128, BK=64, 4 waves (2x2).
// A (x rows) and B (W rows) staged in LDS via 16B DMA, double-buffered,
// XOR-swizzled: LDS slot s of row r holds global 16B-slot (s ^ (r&7)).
// grid (64, 4, 3); z<2 -> row-major out; z==2 -> transposed VT[512][8192].
__global__ __launch_bounds__(256, 2) void qkv_gemm(
    const unsigned short* __restrict__ xb,   // [8192][512] bf16
    const unsigned short* __restrict__ wb,   // [3][512][512] bf16
    const float* __restrict__ biasq, const float* __restrict__ biask,
    const float* __restrict__ biasv,
    unsigned short* __restrict__ Qb, unsigned short* __restrict__ Kb,
    unsigned short* __restrict__ VTb) {
    const int z    = blockIdx.z;
    const int tid  = threadIdx.x;
    const int lane = tid & 63;
    const int w    = tid >> 6;                // wave 0..3
    const int wr   = w >> 1, wc = w & 1;      // 2x2 wave grid (64x64 each)
    const int r0   = blockIdx.x * 128;
    const int c0   = blockIdx.y * 128;
    const unsigned short* wmat = wb + z * 262144;
    const float* bias = (z == 0) ? biasq : (z == 1) ? biask : biasv;
    const int lr  = lane & 15;
    const int lkc = lane >> 4;

    __shared__ unsigned short AB[2][2][128 * 64];   // [A/B][buf][tile] = 64KB

    // staging: thread covers 4 slots per tile; slot L = i*256 + w*64 + lane
    // -> row = L>>3 (= i*32 + w*8 + (lane>>3)), LDS slot = lane&7,
    //    global slot = (lane&7) ^ (row&7) = (lane&7) ^ (lane>>3).
    const int st_row = w * 8 + (lane >> 3);         // + i*32
    const int st_gs  = ((lane & 7) ^ (lane >> 3)) * 8;
    auto stage = [&](int step, int buf) {
        const int kb = step * 64;
#pragma unroll
        for (int i = 0; i < 4; ++i) {
            const int r = i * 32 + st_row;
            cp16(xb   + (size_t)(r0 + r) * 512 + kb + st_gs,
                 &AB[0][buf][(i * 256 + w * 64) * 8]);
            cp16(wmat + (size_t)(c0 + r) * 512 + kb + st_gs,
                 &AB[1][buf][(i * 256 + w * 64) * 8]);
        }
    };

    facc acc[4][4] = {};
    stage(0, 0);
    __syncthreads();

    int buf = 0;
    for (int step = 0; step < 8; ++step) {
        if (step + 1 < 8) stage(step + 1, buf ^ 1);
        bfrag af[4][2], bf4[4][2];
#pragma unroll
        for (int i = 0; i < 4; ++i) {
            const int m = wr * 64 + i * 16 + lr;
            const int mb = m * 64, m7 = m & 7;
            af[i][0] = *(const bfrag*)&AB[0][buf][mb + ((lkc) ^ m7) * 8];
            af[i][1] = *(const bfrag*)&AB[0][buf][mb + ((4 + lkc) ^ m7) * 8];
        }
#pragma unroll
        for (int j = 0; j < 4; ++j) {
            const int n = wc * 64 + j * 16 + lr;
            const int nb = n * 64, n7 = n & 7;
            bf4[j][0] = *(const bfrag*)&AB[1][buf][nb + ((lkc) ^ n7) * 8];
            bf4[j][1] = *(const bfrag*)&AB[1][buf][nb + ((4 + lkc) ^ n7) * 8];
        }
#pragma unroll
        for (int kk = 0; kk < 2; ++kk)
#pragma unroll
            for (int i = 0; i < 4; ++i)
#pragma unroll
                for (int j = 0; j < 4; ++j)
                    acc[i][j] = MFMA16(af[i][kk], bf4[j][kk], acc[i][j]);
        __syncthreads();   // waves done reading buf; next DMA (buf^1) drained
        buf ^= 1;
    }

    // ---- epilogue ----
    if (z < 2) {
        unsigned short* out = (z == 0) ? Qb : Kb;
#pragma unroll
        for (int i = 0; i < 4; ++i)
#pragma unroll
            for (int j = 0; j < 4; ++j) {
                const int col = c0 + wc * 64 + j * 16 + lr;
                const float bv_ = bias[col];
#pragma unroll
                for (int r = 0; r < 4; ++r) {
                    const int row = r0 + wr * 64 + i * 16 + lkc * 4 + r;
                    out[(size_t)row * 512 + col] = f2bf(acc[i][j][r] + bv_);
                }
            }
    } else {
#pragma unroll
        for (int i = 0; i < 4; ++i)
#pragma unroll
            for (int j = 0; j < 4; ++j) {
                const int col = c0 + wc * 64 + j * 16 + lr;
                const float bv_ = bias[col];
                us4v pk;
#pragma unroll
                for (int r = 0; r < 4; ++r) pk[r] = f2bf(acc[i][j][r] + bv_);
                *(us4v*)(VTb + (size_t)col * 8192 + (r0 + wr * 64 + i * 16 + lkc * 4)) = pk;
            }
    }
}

// ------------------------------ flash attention partials -------------------
// 748 blocks (c-major, XCD-chunked), 512 threads (8 waves).
// K tiles staged in LDS by async DMA, double-buffered, XOR-swizzled.
// 2 barriers per tile (C removed: hazards fenced by next iter's A/B).
__global__ __launch_bounds__(512, 2) void attn_partial(
    const unsigned short* __restrict__ Qb, const unsigned short* __restrict__ Kb,
    const unsigned short* __restrict__ VTb,
    unsigned short* __restrict__ Opart, float* __restrict__ ml) {
    // ---- bijective chunked XCD swizzle (m204): consecutive idx -> same XCD
    const int hb   = blockIdx.x;                    // [0,748)
    const int xcd  = hb & 7, pos = hb >> 3;         // q=93, r=4
    const int idx  = (xcd < 4 ? xcd * 94 : 376 + (xcd - 4) * 93) + pos;
    // ---- invert c-major flat order: cum(c) = 134c - 6c^2
    int c = 0;
#pragma unroll
    for (int cc = 1; cc < MAXCH; ++cc)
        if (idx >= 134 * cc - 6 * cc * cc) c = cc;
    const int qb  = 12 * c + (idx - (134 * c - 6 * c * c));
    const int kb0 = c * CCH;
    const int kb1 = min(kb0 + CCH, qb + 1);

    const int tid  = threadIdx.x;
    const int lane = tid & 63;
    const int wv   = tid >> 6;
    const int sr   = wv & 3;     // row strip for QK^T
    const int ch   = wv >> 2;    // col half for QK^T
    const int lr   = lane & 15;
    const int lkc  = lane >> 4;
    const int lk   = lkc * 8;
    const int qrow0 = qb * 64;

    __shared__ unsigned short Klds[2][64 * 512];   // 2 x 64KB, XOR-swizzled rows
    __shared__ float          S_lds[64][65];
    __shared__ unsigned short P_lds[64][72];
    __shared__ float m_lds[64], l_lds[64], sc_lds[64];

    if (tid < 64) { m_lds[tid] = -1e30f; l_lds[tid] = 0.f; }

    // K DMA: wave wv stages rows {wv, wv+8, ..., wv+56}. Within a row the 16B
    // slot s holds global 16B-block (s ^ (row&7)) -> ds_read applies same XOR.
    auto stage_k = [&](int kb, int buf) {
        const unsigned short* src = Kb + (size_t)kb * (64 * 512) + (lane ^ wv) * 8;
#pragma unroll
        for (int i = 0; i < 8; ++i) {
            const int rl = wv + 8 * i;
            cp16(src + (size_t)rl * 512, &Klds[buf][rl * 512]);
        }
    };

    // Q fragments for this wave's 16-row strip: full K=512
    bfrag q[16];
    {
        const unsigned short* qp = Qb + (size_t)(qrow0 + sr * 16 + lr) * 512 + lk;
#pragma unroll
        for (int s = 0; s < 16; ++s) q[s] = *(const bfrag*)(qp + s * 32);
    }
    facc o[4][4] = {};
    stage_k(kb0, 0);
    __syncthreads();

    const int row = tid >> 3;     // softmax: 8 threads per row
    const int sub = tid & 7;
    const float sm_scale = 0.044194173824159216f;   // 1/sqrt(512)
    int cur = 0;

    for (int kb = kb0; kb < kb1; ++kb) {
        const int cb = kb * 64;
        // ---- prefetch next K tile (async, drained at barrier A)
        if (kb + 1 < kb1) stage_k(kb + 1, cur ^ 1);
        // ---- hoist V loads for this tile (consumed at PV)
        bfrag vbf[2][4];
#pragma unroll
        for (int s = 0; s < 2; ++s)
#pragma unroll
            for (int j = 0; j < 4; ++j)
                vbf[s][j] = *(const bfrag*)(VTb + (size_t)(wv * 64 + j * 16 + lr) * 8192
                                            + cb + s * 32 + lk);
        // ---- QK^T from LDS (two interleaved acc chains per tc: depth 16->8)
#pragma unroll
        for (int tc = 0; tc < 2; ++tc) {
            facc sa0 = {}, sa1 = {};
            const int rl = ch * 32 + tc * 16 + lr;
            const unsigned short* kbase = &Klds[cur][rl * 512];
            const int rx = rl & 7;
#pragma unroll
            for (int s = 0; s < 16; s += 2) {
                const int sl0 = (s * 4 + lkc) ^ rx;
                const int sl1 = ((s + 1) * 4 + lkc) ^ rx;
                sa0 = MFMA16(q[s],     *(const bfrag*)(kbase + sl0 * 8), sa0);
                sa1 = MFMA16(q[s + 1], *(const bfrag*)(kbase + sl1 * 8), sa1);
            }
#pragma unroll
            for (int r = 0; r < 4; ++r)
                S_lds[sr * 16 + lkc * 4 + r][ch * 32 + tc * 16 + lr] = sa0[r] + sa1[r];
        }
        __syncthreads();   // A: S complete (+ drains next-K DMA & V loads)

        // ---- online softmax (rows of 64 cols; 8 threads/row) ----
        {
            const int grow  = qrow0 + row;
            const bool diag = (kb == qb);
            float sv[8];
#pragma unroll
            for (int j = 0; j < 8; ++j) {
                float v = S_lds[row][sub * 8 + j] * sm_scale;
                if (diag && (cb + sub * 8 + j > grow)) v = -1e30f;
                sv[j] = v;
            }
            float mx = sv[0];
#pragma unroll
            for (int j = 1; j < 8; ++j) mx = fmaxf(mx, sv[j]);
            mx = fmaxf(mx, __shfl_xor(mx, 1));
            mx = fmaxf(mx, __shfl_xor(mx, 2));
            mx = fmaxf(mx, __shfl_xor(mx, 4));
            const float m_old = m_lds[row];
            const float m_new = fmaxf(m_old, mx);
            float sum = 0.f;
            bfrag pv_;
#pragma unroll
            for (int j = 0; j < 8; ++j) {
                float p = __expf(sv[j] - m_new);
                sum += p;
                pv_[j] = (short)f2bf(p);
            }
            sum += __shfl_xor(sum, 1);
            sum += __shfl_xor(sum, 2);
            sum += __shfl_xor(sum, 4);
            if (sub == 0) {                          // single writer
                const float scl = __expf(m_old - m_new);
                sc_lds[row] = scl;
                m_lds[row]  = m_new;
                l_lds[row]  = l_lds[row] * scl + sum;
            }
            *(bfrag*)(&P_lds[row][sub * 8]) = pv_;   // 16B aligned (144B stride)
        }
        __syncthreads();   // B: P, m/l/sc complete

        // ---- rescale accumulators ----
#pragma unroll
        for (int i = 0; i < 4; ++i) {
            float s0 = sc_lds[i * 16 + lkc * 4 + 0];
            float s1 = sc_lds[i * 16 + lkc * 4 + 1];
            float s2 = sc_lds[i * 16 + lkc * 4 + 2];
            float s3 = sc_lds[i * 16 + lkc * 4 + 3];
#pragma unroll
            for (int j = 0; j < 4; ++j) {
                o[i][j][0] *= s0; o[i][j][1] *= s1;
                o[i][j][2] *= s2; o[i][j][3] *= s3;
            }
        }
        // ---- PV: O[:, 64w..] += P @ V (V frags already in regs) ----
        // (no trailing barrier: next QK^T touches only Klds; P/S/m/l hazards
        //  are write-after-read fenced by next iter's barriers A/B)
#pragma unroll
        for (int s = 0; s < 2; ++s) {
            bfrag pa[4];
#pragma unroll
            for (int i = 0; i < 4; ++i)
                pa[i] = *(const bfrag*)(&P_lds[i * 16 + lr][s * 32 + lk]);
#pragma unroll
            for (int i = 0; i < 4; ++i)
#pragma unroll
                for (int j = 0; j < 4; ++j)
                    o[i][j] = MFMA16(pa[i], vbf[s][j], o[i][j]);
        }
        cur ^= 1;
    }

    // ---- epilogue: unnormalized partial O (bf16) + m/l stats ----
    {
        const size_t obase = (size_t)idx * (64 * 512);
#pragma unroll
        for (int i = 0; i < 4; ++i)
#pragma unroll
            for (int j = 0; j < 4; ++j) {
                const int colb = wv * 64 + j * 16 + lr;
#pragma unroll
                for (int r = 0; r < 4; ++r) {
                    const int rrow = i * 16 + lkc * 4 + r;
                    Opart[obase + (size_t)rrow * 512 + colb] = f2bf(o[i][j][r]);
                }
            }
        if (tid < 64) {
            ml[(size_t)idx * 128 + tid * 2 + 0] = m_lds[tid];
            ml[(size_t)idx * 128 + tid * 2 + 1] = l_lds[tid];
        }
    }
}

// ------------------------------ split-KV combine ---------------------------
// grid (128, 8): block = (qb, 8-row group). Inner chunk loop is compile-time
// (11 iters, zero-weighted beyond nch) -> 88 independent loads per thread.
__global__ __launch_bounds__(256) void combine_k(
    const unsigned short* __restrict__ Opart, const float* __restrict__ ml,
    float* __restrict__ out) {
    const int qb  = blockIdx.x;
    const int rg  = blockIdx.y;            // 8-row group within the 64-row qb
    const int nch = qb / 12 + 1;
    const int tid = threadIdx.x;
    __shared__ float wts[MAXCH][8];

    if (tid < 8) {
        const int lrow = rg * 8 + tid;     // local row in [0,64)
        float M = -1e30f;
        for (int cc = 0; cc < nch; ++cc)
            M = fmaxf(M, ml[(size_t)part_idx(qb, cc) * 128 + lrow * 2]);
        float den = 0.f;
        for (int cc = 0; cc < nch; ++cc) {
            float mc = ml[(size_t)part_idx(qb, cc) * 128 + lrow * 2];
            float lc = ml[(size_t)part_idx(qb, cc) * 128 + lrow * 2 + 1];
            den += lc * __expf(mc - M);
        }
        const float inv = 1.f / den;
#pragma unroll
        for (int cc = 0; cc < MAXCH; ++cc)
            wts[cc][tid] = (cc < nch)
                ? __expf(ml[(size_t)part_idx(qb, cc) * 128 + lrow * 2] - M) * inv
                : 0.f;
    }
    __syncthreads();

    float a0[8] = {}, a1[8] = {};
#pragma unroll
    for (int cc = 0; cc < MAXCH; ++cc) {
        // part_idx is always in [0,748) even for cc>=nch (weight 0, data finite)
        const size_t base = (size_t)part_idx(qb, cc) * (64 * 512);
#pragma unroll
        for (int r = 0; r < 8; ++r) {
            const unsigned int pk = *(const unsigned int*)(
                Opart + base + (size_t)(rg * 8 + r) * 512 + tid * 2);
            const float w = wts[cc][r];
            a0[r] += w * bf2f(pk & 0xffffu);
            a1[r] += w * bf2f(pk >> 16);
        }
    }
#pragma unroll
    for (int r = 0; r < 8; ++r) {
        f32x2v res; res[0] = a0[r]; res[1] = a1[r];
        *(f32x2v*)(out + (size_t)(qb * 64 + rg * 8 + r) * 512 + tid * 2) = res;
    }
}

// ------------------------------ launcher -----------------------------------
extern "C" void kernel_launch(void* const* d_in, const int* in_sizes, int n_in,
                              void* d_out, int out_size, void* d_ws, size_t ws_size,
                              hipStream_t stream) {
    const float* x  = (const float*)d_in[0];
    // d_in[1] = mask: deliberately unread (causal mask computed implicitly)
    const float* Wq = (const float*)d_in[2];
    const float* bq = (const float*)d_in[3];
    const float* Wk = (const float*)d_in[4];
    const float* bk = (const float*)d_in[5];
    const float* Wv = (const float*)d_in[6];
    const float* bv = (const float*)d_in[7];
    float* out = (float*)d_out;

    char* ws = (char*)d_ws;
    unsigned short* xb  = (unsigned short*)(ws);                 //  8 MB
    unsigned short* Wb  = (unsigned short*)(ws + 8388608);       //  1.5 MB
    unsigned short* Qb  = (unsigned short*)(ws + 9961472);       //  8 MB
    unsigned short* Kb  = (unsigned short*)(ws + 18350080);      //  8 MB
    unsigned short* VTb = (unsigned short*)(ws + 26738688);      //  8 MB
    unsigned short* Op  = (unsigned short*)(ws + 35127296);      // 46.7 MB
    float*          mlp = (float*)(ws + 84148224);               //  0.37 MB

    hipLaunchKernelGGL(cvt_x_kernel, dim3(4096), dim3(256), 0, stream, x, xb, 1048576);
    hipLaunchKernelGGL(cvt_w_kernel, dim3(768), dim3(256), 0, stream, Wq, Wk, Wv, Wb);
    hipLaunchKernelGGL(qkv_gemm, dim3(64, 4, 3), dim3(256), 0, stream,
                       xb, Wb, bq, bk, bv, Qb, Kb, VTb);
    hipLaunchKernelGGL(attn_partial, dim3(NCHTOT), dim3(512), 0, stream,
                       Qb, Kb, VTb, Op, mlp);
    hipLaunchKernelGGL(combine_k, dim3(NQB, 8), dim3(256), 0, stream, Op, mlp, out);
}